// Round 14
// baseline (84.181 us; speedup 1.0000x reference)
//
#include <hip/hip_runtime.h>
#include <hip/hip_bf16.h>
#include <stdint.h>

#define S_LEN  2048
#define DMODEL 1024
#define NHEADS 16
#define HDIM   64
#define CHUNK  5      // k-tiles (64 keys) per attention chunk-block
#define NCHUNK 32     // sum over 8 q-tiles (256 rows) of ceil(4*(qt+1)/CHUNK)
#define LOG2E  1.4426950408889634f

typedef __attribute__((ext_vector_type(8))) _Float16 half8;
typedef __attribute__((ext_vector_type(4))) _Float16 half4;
typedef __attribute__((ext_vector_type(4))) float    f32x4;

struct AttnMap { int base[9]; };

// ---------------- fp32 -> fp16 convert (7 tensors, one launch) ----------------
struct CvtArgs {
    const float* src[7];
    _Float16*    dst[7];
    int          n[7];
};

__global__ __launch_bounds__(256) void cvt_kernel(CvtArgs a) {
    const int z = blockIdx.z;
    const float* __restrict__ src = a.src[z];
    _Float16* __restrict__ dst = a.dst[z];
    const int n = a.n[z];
    const int stride = gridDim.x * blockDim.x * 8;
    for (int i = (blockIdx.x * blockDim.x + threadIdx.x) * 8; i < n; i += stride) {
        float4 v0 = *(const float4*)(src + i);
        float4 v1 = *(const float4*)(src + i + 4);
        half8 o;
        o[0] = (_Float16)v0.x; o[1] = (_Float16)v0.y;
        o[2] = (_Float16)v0.z; o[3] = (_Float16)v0.w;
        o[4] = (_Float16)v1.x; o[5] = (_Float16)v1.y;
        o[6] = (_Float16)v1.z; o[7] = (_Float16)v1.w;
        *(half8*)(dst + i) = o;
    }
}

// ---------------- GEMM: C[2048][1024] = A x W^T + bias ----------------
// R9-proven structure: BM x 64 tile, BK=64, 4 waves (2x2). Double-buffered
// LDS, 2-phase pipeline. Both-sides XOR swizzle on 128B LDS rows.
// XCD-contiguous 1-D grid remap. TRANS mode writes C^T (fused V transpose).
// NO setprio here (m190: null-to-negative on lockstep barrier-synced GEMM).
__device__ __forceinline__ void gload16(const _Float16* g, _Float16* l) {
    __builtin_amdgcn_global_load_lds(
        (__attribute__((address_space(1))) void*)const_cast<_Float16*>(g),
        (__attribute__((address_space(3))) void*)l, 16, 0, 0);
}

template<int BM, typename OT>
__device__ __forceinline__ void gemm_body(
    const _Float16* __restrict__ A,
    const _Float16* __restrict__ W,
    const float*    __restrict__ bias,
    OT* __restrict__ C, float scale, int bx, int by, bool trans)
{
    constexpr int FI = BM / 32;
    __shared__ _Float16 As[2][BM * 64];
    __shared__ _Float16 Bs[2][64 * 64];
    const int tid  = threadIdx.x;
    const int lane = tid & 63, wid = tid >> 6;
    const int row0 = by * BM;
    const int col0 = bx * 64;
    const int wr = wid >> 1, wc = wid & 1;
    const int lr = lane & 15, lg = lane >> 4;
    const int sl = lane & 7;

    f32x4 acc[FI][2];
#pragma unroll
    for (int i = 0; i < FI; i++)
#pragma unroll
        for (int j = 0; j < 2; j++) acc[i][j] = (f32x4)(0.0f);

    auto stage = [&](int b, int k0) {
#pragma unroll
        for (int r = 0; r < BM / 32; r++) {
            const int base = r * 256 + wid * 64;
            const int row  = (base + lane) >> 3;
            gload16(A + (size_t)(row0 + row) * DMODEL + k0 + ((sl ^ (row & 7)) * 8),
                    &As[b][(size_t)base * 8]);
        }
#pragma unroll
        for (int r = 0; r < 2; r++) {
            const int base = r * 256 + wid * 64;
            const int row  = (base + lane) >> 3;
            gload16(W + (size_t)(col0 + row) * DMODEL + k0 + ((sl ^ (row & 7)) * 8),
                    &Bs[b][(size_t)base * 8]);
        }
    };

    stage(0, 0);
    __syncthreads();
    int cur = 0;
    for (int t = 0; t < DMODEL / 64; t++) {
        if (t + 1 < DMODEL / 64) stage(cur ^ 1, (t + 1) * 64);
#pragma unroll
        for (int ks = 0; ks < 2; ks++) {
            half8 af[FI], bf[2];
#pragma unroll
            for (int i = 0; i < FI; i++)
                af[i] = *(const half8*)(&As[cur][(wr * (BM / 2) + i * 16 + lr) * 64 + (((ks * 4 + lg) ^ (lr & 7)) * 8)]);
#pragma unroll
            for (int j = 0; j < 2; j++)
                bf[j] = *(const half8*)(&Bs[cur][(wc * 32 + j * 16 + lr) * 64 + (((ks * 4 + lg) ^ (lr & 7)) * 8)]);
#pragma unroll
            for (int i = 0; i < FI; i++)
#pragma unroll
                for (int j = 0; j < 2; j++)
                    acc[i][j] = __builtin_amdgcn_mfma_f32_16x16x32_f16(af[i], bf[j], acc[i][j], 0, 0, 0);
        }
        __syncthreads();
        cur ^= 1;
    }
#pragma unroll
    for (int i = 0; i < FI; i++)
#pragma unroll
        for (int j = 0; j < 2; j++) {
            const int row = row0 + wr * (BM / 2) + i * 16 + lg * 4;
            const int col = col0 + wc * 32 + j * 16 + lr;
            const float b = bias[col];
            if (trans) {   // fused transpose: C^T[col][row..row+3] (fp16 only)
                half4 h;
#pragma unroll
                for (int rj = 0; rj < 4; rj++) h[rj] = (_Float16)((acc[i][j][rj] + b) * scale);
                *(half4*)((_Float16*)C + (size_t)col * S_LEN + row) = h;
            } else {
#pragma unroll
                for (int rj = 0; rj < 4; rj++) {
                    float v = (acc[i][j][rj] + b) * scale;
                    if constexpr (sizeof(OT) == 2)
                        C[(size_t)(row + rj) * DMODEL + col] = (OT)(_Float16)v;
                    else
                        C[(size_t)(row + rj) * DMODEL + col] = v;
                }
            }
        }
}

struct QKVArgs {
    const _Float16* A[3];
    const _Float16* W[3];
    const float*    bias[3];
    _Float16*       C[3];
    float           scale[3];
};

// grid 768: XCD remap -> sid; sid -> (z, by, bx), bx fastest (A-panel L2 reuse).
// z==2 (v projection) writes transposed -> Vt directly (no transpose kernel).
__global__ __launch_bounds__(256) void gemm_qkv(QKVArgs a) {
    const int nper = (int)gridDim.x >> 3;
    const int sid  = ((int)blockIdx.x & 7) * nper + ((int)blockIdx.x >> 3);
    const int z  = sid >> 8;
    const int r  = sid & 255;
    const int by = r >> 4, bx = r & 15;
    gemm_body<128, _Float16>(a.A[z], a.W[z], a.bias[z], a.C[z], a.scale[z], bx, by, z == 2);
}

__global__ __launch_bounds__(256) void gemm_out_k(const _Float16* __restrict__ A,
                                                  const _Float16* __restrict__ W,
                                                  const float* __restrict__ bias,
                                                  float* __restrict__ C) {
    const int nper = (int)gridDim.x >> 3;
    const int sid  = ((int)blockIdx.x & 7) * nper + ((int)blockIdx.x >> 3);
    const int by = sid >> 4, bx = sid & 15;
    gemm_body<64, float>(A, W, bias, C, 1.0f, bx, by, false);
}

// ---------------- causal flash attention ----------------
// R9-proven grid: (NCHUNK, NHEADS) 2-D, heavy chunks first (remap family
// regressed twice -> reverted permanently). 512 thr = 8 waves x 32 q-rows.
// Each K/V ds_read feeds TWO MFMAs. LDS-staged K/V double-buffered.
// Swapped mfma(K,Q), exp2 domain, defer-max THR=8. setprio kept (m191: +4-7%).
__global__ __launch_bounds__(512, 4) void attn_kernel(
    const _Float16* __restrict__ q,
    const _Float16* __restrict__ k,
    const _Float16* __restrict__ Vt,
    _Float16* __restrict__ Opart,   // [16][NCHUNK][256][64], normalized
    float2* __restrict__ ml,        // [16][NCHUNK][256]
    AttnMap map)
{
    __shared__ _Float16 Kl[2][64 * 64];
    __shared__ _Float16 Vl[2][64 * 64];
    __shared__ _Float16 P[8][32][72];
    const int tid = threadIdx.x, lane = tid & 63, wid = tid >> 6;
    const int x = NCHUNK - 1 - (int)blockIdx.x;   // heavy chunks first
    const int h = blockIdx.y;
    int qt = 0;
    while (map.base[qt + 1] <= x) qt++;
    const int c  = x - map.base[qt];
    const int q0 = qt * 256 + wid * 32;
    const int lr = lane & 15, lg = lane >> 4;
    const int srcb = lg * 20;

    const int r8 = lane >> 3, sl = lane & 7;
    const int ssw = (sl ^ r8) * 8;

    half8 qf[2][2];
#pragma unroll
    for (int qs = 0; qs < 2; qs++)
#pragma unroll
        for (int ds = 0; ds < 2; ds++)
            qf[qs][ds] = *(const half8*)(q + (size_t)(q0 + qs * 16 + lr) * DMODEL + h * HDIM + ds * 32 + lg * 8);

    float m[2] = {-1e30f, -1e30f}, lsum[2] = {0.0f, 0.0f};
    f32x4 od[2][4];
#pragma unroll
    for (int qs = 0; qs < 2; qs++)
#pragma unroll
        for (int dt = 0; dt < 4; dt++) od[qs][dt] = (f32x4)(0.0f);

    const int T4 = 4 * (qt + 1);
    const int t0 = c * CHUNK;
    const int t1 = (T4 < t0 + CHUNK) ? T4 : (t0 + CHUNK);

    auto stage = [&](int b, int t) {
        const int kb = t * 64;
        gload16(k + (size_t)(kb + wid * 8 + r8) * DMODEL + h * HDIM + ssw,
                &Kl[b][wid * 8 * 64]);
        gload16(Vt + (size_t)(h * HDIM + wid * 8 + r8) * S_LEN + kb + ssw,
                &Vl[b][wid * 8 * 64]);
    };

    int cur = 0;
    stage(0, t0);
    __syncthreads();

    for (int t = t0; t < t1; t++) {
        if (t + 1 < t1) stage(cur ^ 1, t + 1);
        const int k0 = t * 64;
        f32x4 sc[2][4];
#pragma unroll
        for (int qs = 0; qs < 2; qs++)
#pragma unroll
            for (int kt = 0; kt < 4; kt++) sc[qs][kt] = (f32x4)(0.0f);
        __builtin_amdgcn_s_setprio(1);
#pragma unroll
        for (int kt = 0; kt < 4; kt++)
#pragma unroll
            for (int ds = 0; ds < 2; ds++) {
                half8 kf = *(const half8*)(&Kl[cur][(kt * 16 + lr) * 64 + (((ds * 4 + lg) ^ (lr & 7)) * 8)]);
                sc[0][kt] = __builtin_amdgcn_mfma_f32_16x16x32_f16(kf, qf[0][ds], sc[0][kt], 0, 0, 0);
                sc[1][kt] = __builtin_amdgcn_mfma_f32_16x16x32_f16(kf, qf[1][ds], sc[1][kt], 0, 0, 0);
            }
        __builtin_amdgcn_s_setprio(0);
        // sc[qs][kt][r] = S[key=k0+kt*16+lg*4+r][q=q0+qs*16+lr]
        if (k0 + 63 > q0) {
#pragma unroll
            for (int qs = 0; qs < 2; qs++) {
                const int qrow = q0 + qs * 16 + lr;
#pragma unroll
                for (int kt = 0; kt < 4; kt++) {
                    const int kb2 = k0 + kt * 16 + lg * 4;
#pragma unroll
                    for (int r = 0; r < 4; r++)
                        if (kb2 + r > qrow) sc[qs][kt][r] = -1e30f;
                }
            }
        }
        float vmax[2];
#pragma unroll
        for (int qs = 0; qs < 2; qs++) {
            float mk[4];
#pragma unroll
            for (int kt = 0; kt < 4; kt++)
                mk[kt] = fmaxf(fmaxf(sc[qs][kt][0], sc[qs][kt][1]), fmaxf(sc[qs][kt][2], sc[qs][kt][3]));
            float v = fmaxf(fmaxf(mk[0], mk[1]), fmaxf(mk[2], mk[3]));
            v = fmaxf(v, __shfl_xor(v, 16));
            v = fmaxf(v, __shfl_xor(v, 32));
            vmax[qs] = v;
        }
        if (!__all(vmax[0] <= m[0] + 8.0f && vmax[1] <= m[1] + 8.0f)) {   // T13
#pragma unroll
            for (int qs = 0; qs < 2; qs++) {
                const float mnew = fmaxf(m[qs], vmax[qs]);
                const float sfac = exp2f(m[qs] - mnew);
                m[qs] = mnew;
                lsum[qs] *= sfac;
                float sf[4];
#pragma unroll
                for (int r = 0; r < 4; r++) sf[r] = __shfl(sfac, srcb + r);
#pragma unroll
                for (int dt = 0; dt < 4; dt++)
#pragma unroll
                    for (int r = 0; r < 4; r++) od[qs][dt][r] *= sf[r];
            }
        }
#pragma unroll
        for (int qs = 0; qs < 2; qs++) {
            float ps[4];
#pragma unroll
            for (int kt = 0; kt < 4; kt++) {
                float p0 = exp2f(sc[qs][kt][0] - m[qs]), p1 = exp2f(sc[qs][kt][1] - m[qs]);
                float p2 = exp2f(sc[qs][kt][2] - m[qs]), p3 = exp2f(sc[qs][kt][3] - m[qs]);
                sc[qs][kt][0] = p0; sc[qs][kt][1] = p1; sc[qs][kt][2] = p2; sc[qs][kt][3] = p3;
                ps[kt] = (p0 + p1) + (p2 + p3);
            }
            float psum = (ps[0] + ps[1]) + (ps[2] + ps[3]);
            psum += __shfl_xor(psum, 16);
            psum += __shfl_xor(psum, 32);
            lsum[qs] += psum;
#pragma unroll
            for (int kt = 0; kt < 4; kt++) {
                half4 ph;
#pragma unroll
                for (int r = 0; r < 4; r++) ph[r] = (_Float16)sc[qs][kt][r];
                *(half4*)(&P[wid][qs * 16 + lr][kt * 16 + lg * 4]) = ph;
            }
        }
        __builtin_amdgcn_s_setprio(1);
#pragma unroll
        for (int ks = 0; ks < 2; ks++) {
            half8 pa0 = *(const half8*)(&P[wid][lr][ks * 32 + lg * 8]);
            half8 pa1 = *(const half8*)(&P[wid][16 + lr][ks * 32 + lg * 8]);
#pragma unroll
            for (int dt = 0; dt < 4; dt++) {
                half8 vb = *(const half8*)(&Vl[cur][(dt * 16 + lr) * 64 + (((ks * 4 + lg) ^ (lr & 7)) * 8)]);
                od[0][dt] = __builtin_amdgcn_mfma_f32_16x16x32_f16(pa0, vb, od[0][dt], 0, 0, 0);
                od[1][dt] = __builtin_amdgcn_mfma_f32_16x16x32_f16(pa1, vb, od[1][dt], 0, 0, 0);
            }
        }
        __builtin_amdgcn_s_setprio(0);
        __syncthreads();
        cur ^= 1;
    }

    _Float16* Ob = Opart + ((size_t)h * NCHUNK + x) * 256 * 64;
#pragma unroll
    for (int qs = 0; qs < 2; qs++) {
        const float inv = 1.0f / lsum[qs];
        float invb[4];
#pragma unroll
        for (int r = 0; r < 4; r++) invb[r] = __shfl(inv, srcb + r);
#pragma unroll
        for (int dt = 0; dt < 4; dt++)
#pragma unroll
            for (int r = 0; r < 4; r++)
                Ob[(size_t)(wid * 32 + qs * 16 + lg * 4 + r) * 64 + dt * 16 + lr] =
                    (_Float16)(od[qs][dt][r] * invb[r]);
    }
    if (lane < 16) {
#pragma unroll
        for (int qs = 0; qs < 2; qs++) {
            float2 v; v.x = m[qs]; v.y = lsum[qs];
            ml[((size_t)h * NCHUNK + x) * 256 + wid * 32 + qs * 16 + lr] = v;
        }
    }
}

// ---------------- chunk combine: at[q][h*64+d] fp16 ----------------
__global__ __launch_bounds__(256) void combine_kernel(
    const _Float16* __restrict__ Opart, const float2* __restrict__ ml,
    _Float16* __restrict__ at, AttnMap map)
{
    const int idx = blockIdx.x * 256 + threadIdx.x;
    const int qrow = idx >> 7;
    const int c8 = (idx & 127) * 8;
    const int h = c8 >> 6, d = c8 & 63;
    const int qt = qrow >> 8;
    const int cb = map.base[qt];
    const int nc = map.base[qt + 1] - cb;
    const int lrow = qrow & 255;

    float M = -1e30f, denom = 0.0f;
    float acc[8];
#pragma unroll
    for (int j = 0; j < 8; j++) acc[j] = 0.0f;
    for (int cc = 0; cc < nc; cc++) {
        const size_t ci = (size_t)h * NCHUNK + cb + cc;
        const float2 mlv = ml[ci * 256 + lrow];
        half8 ov = *(const half8*)(Opart + (ci * 256 + lrow) * 64 + d);
        if (mlv.x > M) {
            const float r = exp2f(M - mlv.x);
            denom = denom * r + mlv.y;
#pragma unroll
            for (int j = 0; j < 8; j++) acc[j] = acc[j] * r + (float)ov[j] * mlv.y;
            M = mlv.x;
        } else {
            const float w = exp2f(mlv.x - M) * mlv.y;
            denom += w;
#pragma unroll
            for (int j = 0; j < 8; j++) acc[j] += (float)ov[j] * w;
        }
    }
    const float inv = 1.0f / denom;
    half8 o;
#pragma unroll
    for (int j = 0; j < 8; j++) o[j] = (_Float16)(acc[j] * inv);
    *(half8*)(at + (size_t)qrow * DMODEL + c8) = o;
}

// ---------------- launch ----------------
extern "C" void kernel_launch(void* const* d_in, const int* in_sizes, int n_in,
                              void* d_out, int out_size, void* d_ws, size_t ws_size,
                              hipStream_t stream) {
    const float* Q  = (const float*)d_in[0];
    const float* K  = (const float*)d_in[1];
    const float* V  = (const float*)d_in[2];
    const float* Wq = (const float*)d_in[3];
    const float* bq = (const float*)d_in[4];
    const float* Wk = (const float*)d_in[5];
    const float* bk = (const float*)d_in[6];
    const float* Wv = (const float*)d_in[7];
    const float* bv = (const float*)d_in[8];
    const float* Wo = (const float*)d_in[9];
    const float* bo = (const float*)d_in[10];

    // 32 MB workspace, liveness-aliased (MB offsets):
    //  0-4  : Vt  (qkv z2 transposed out -> attn)
    //  4-8  : qh  (qkv -> attn)          -> at (combine -> gemm_out)
    //  8-12 : kh  (qkv -> attn)
    // 12-14 : Woh (cvt -> gemm_out)
    // 14-30 : Qh/Kh/Vh/Wqh/Wkh (cvt -> qkv) -> Opart(16MB) (attn -> combine)
    // 30-32 : Wvh (cvt -> qkv)              -> ml(1MB)     (attn -> combine)
    char* w = (char*)d_ws;
    const size_t MB = 1 << 20;
    _Float16* Vt  = (_Float16*)(w + 0 * MB);
    _Float16* qh  = (_Float16*)(w + 4 * MB);
    _Float16* kh  = (_Float16*)(w + 8 * MB);
    _Float16* Woh = (_Float16*)(w + 12 * MB);
    _Float16* Qh  = (_Float16*)(w + 14 * MB);
    _Float16* Kh  = (_Float16*)(w + 18 * MB);
    _Float16* Vh  = (_Float16*)(w + 22 * MB);
    _Float16* Wqh = (_Float16*)(w + 26 * MB);
    _Float16* Wkh = (_Float16*)(w + 28 * MB);
    _Float16* Wvh = (_Float16*)(w + 30 * MB);
    _Float16* Opart = (_Float16*)(w + 14 * MB);   // 16 MB exactly
    float2*   ml    = (float2*)(w + 30 * MB);     // 1 MB
    _Float16* at    = qh;

    const size_t SD = (size_t)S_LEN * DMODEL;
    const size_t WD = (size_t)DMODEL * DMODEL;

    CvtArgs ca;
    ca.src[0] = Q;  ca.dst[0] = Qh;  ca.n[0] = (int)SD;
    ca.src[1] = K;  ca.dst[1] = Kh;  ca.n[1] = (int)SD;
    ca.src[2] = V;  ca.dst[2] = Vh;  ca.n[2] = (int)SD;
    ca.src[3] = Wq; ca.dst[3] = Wqh; ca.n[3] = (int)WD;
    ca.src[4] = Wk; ca.dst[4] = Wkh; ca.n[4] = (int)WD;
    ca.src[5] = Wv; ca.dst[5] = Wvh; ca.n[5] = (int)WD;
    ca.src[6] = Wo; ca.dst[6] = Woh; ca.n[6] = (int)WD;
    cvt_kernel<<<dim3(512, 1, 7), 256, 0, stream>>>(ca);

    QKVArgs ga;
    ga.A[0] = Qh; ga.W[0] = Wqh; ga.bias[0] = bq; ga.C[0] = qh; ga.scale[0] = 0.125f * LOG2E;
    ga.A[1] = Kh; ga.W[1] = Wkh; ga.bias[1] = bk; ga.C[1] = kh; ga.scale[1] = 1.0f;
    ga.A[2] = Vh; ga.W[2] = Wvh; ga.bias[2] = bv; ga.C[2] = Vt; ga.scale[2] = 1.0f;
    gemm_qkv<<<dim3(768), 256, 0, stream>>>(ga);

    AttnMap map;
    map.base[0] = 0;
    for (int qt = 0; qt < 8; qt++)
        map.base[qt + 1] = map.base[qt] + (4 * (qt + 1) + CHUNK - 1) / CHUNK;
    // map.base[8] == NCHUNK (32)

    attn_kernel<<<dim3(NCHUNK, NHEADS), 512, 0, stream>>>(qh, kh, Vt, Opart, ml, map);
    combine_kernel<<<dim3(1024), 256, 0, stream>>>(Opart, ml, at, map);
    gemm_out_k<<<dim3(512), 256, 0, stream>>>(at, Woh, bo, (float*)d_out);
}

// Round 15
// 79.598 us; speedup vs baseline: 1.0576x; 1.0576x over previous
//
#include <hip/hip_runtime.h>
#include <hip/hip_bf16.h>
#include <stdint.h>

#define S_LEN  2048
#define DMODEL 1024
#define NHEADS 16
#define HDIM   64
#define CHUNK  5      // k-tiles (64 keys) per attention chunk-block
#define NCHUNK 32     // sum over 8 q-tiles (256 rows) of ceil(4*(qt+1)/CHUNK)
#define LOG2E  1.4426950408889634f

typedef __attribute__((ext_vector_type(8))) _Float16 half8;
typedef __attribute__((ext_vector_type(4))) _Float16 half4;
typedef __attribute__((ext_vector_type(4))) float    f32x4;

struct AttnMap { int base[9]; };

// ---------------- fp32 -> fp16 convert (7 tensors, one launch) ----------------
struct CvtArgs {
    const float* src[7];
    _Float16*    dst[7];
    int          n[7];
};

__global__ __launch_bounds__(256) void cvt_kernel(CvtArgs a) {
    const int z = blockIdx.z;
    const float* __restrict__ src = a.src[z];
    _Float16* __restrict__ dst = a.dst[z];
    const int n = a.n[z];
    const int stride = gridDim.x * blockDim.x * 8;
    for (int i = (blockIdx.x * blockDim.x + threadIdx.x) * 8; i < n; i += stride) {
        float4 v0 = *(const float4*)(src + i);
        float4 v1 = *(const float4*)(src + i + 4);
        half8 o;
        o[0] = (_Float16)v0.x; o[1] = (_Float16)v0.y;
        o[2] = (_Float16)v0.z; o[3] = (_Float16)v0.w;
        o[4] = (_Float16)v1.x; o[5] = (_Float16)v1.y;
        o[6] = (_Float16)v1.z; o[7] = (_Float16)v1.w;
        *(half8*)(dst + i) = o;
    }
}

// ---------------- GEMM: C[2048][1024] = A x W^T + bias ----------------
// R9-exact (best measured: 79.6us): BM x 64 tile, BK=64, 4 waves (2x2).
// Double-buffered LDS, 2-phase pipeline (stage(t+1) BEFORE compute(t), one
// __syncthreads per k-tile). Both-sides XOR swizzle on 128B LDS rows.
// XCD-contiguous 1-D grid remap. setprio around MFMA cluster (R14 A/B:
// removing it cost ~4us). TRANS mode writes C^T (fused V transpose).
__device__ __forceinline__ void gload16(const _Float16* g, _Float16* l) {
    __builtin_amdgcn_global_load_lds(
        (__attribute__((address_space(1))) void*)const_cast<_Float16*>(g),
        (__attribute__((address_space(3))) void*)l, 16, 0, 0);
}

template<int BM, typename OT>
__device__ __forceinline__ void gemm_body(
    const _Float16* __restrict__ A,
    const _Float16* __restrict__ W,
    const float*    __restrict__ bias,
    OT* __restrict__ C, float scale, int bx, int by, bool trans)
{
    constexpr int FI = BM / 32;
    __shared__ _Float16 As[2][BM * 64];
    __shared__ _Float16 Bs[2][64 * 64];
    const int tid  = threadIdx.x;
    const int lane = tid & 63, wid = tid >> 6;
    const int row0 = by * BM;
    const int col0 = bx * 64;
    const int wr = wid >> 1, wc = wid & 1;
    const int lr = lane & 15, lg = lane >> 4;
    const int sl = lane & 7;

    f32x4 acc[FI][2];
#pragma unroll
    for (int i = 0; i < FI; i++)
#pragma unroll
        for (int j = 0; j < 2; j++) acc[i][j] = (f32x4)(0.0f);

    auto stage = [&](int b, int k0) {
#pragma unroll
        for (int r = 0; r < BM / 32; r++) {
            const int base = r * 256 + wid * 64;
            const int row  = (base + lane) >> 3;
            gload16(A + (size_t)(row0 + row) * DMODEL + k0 + ((sl ^ (row & 7)) * 8),
                    &As[b][(size_t)base * 8]);
        }
#pragma unroll
        for (int r = 0; r < 2; r++) {
            const int base = r * 256 + wid * 64;
            const int row  = (base + lane) >> 3;
            gload16(W + (size_t)(col0 + row) * DMODEL + k0 + ((sl ^ (row & 7)) * 8),
                    &Bs[b][(size_t)base * 8]);
        }
    };

    stage(0, 0);
    __syncthreads();
    int cur = 0;
    for (int t = 0; t < DMODEL / 64; t++) {
        if (t + 1 < DMODEL / 64) stage(cur ^ 1, (t + 1) * 64);
#pragma unroll
        for (int ks = 0; ks < 2; ks++) {
            half8 af[FI], bf[2];
#pragma unroll
            for (int i = 0; i < FI; i++)
                af[i] = *(const half8*)(&As[cur][(wr * (BM / 2) + i * 16 + lr) * 64 + (((ks * 4 + lg) ^ (lr & 7)) * 8)]);
#pragma unroll
            for (int j = 0; j < 2; j++)
                bf[j] = *(const half8*)(&Bs[cur][(wc * 32 + j * 16 + lr) * 64 + (((ks * 4 + lg) ^ (lr & 7)) * 8)]);
            __builtin_amdgcn_s_setprio(1);
#pragma unroll
            for (int i = 0; i < FI; i++)
#pragma unroll
                for (int j = 0; j < 2; j++)
                    acc[i][j] = __builtin_amdgcn_mfma_f32_16x16x32_f16(af[i], bf[j], acc[i][j], 0, 0, 0);
            __builtin_amdgcn_s_setprio(0);
        }
        __syncthreads();
        cur ^= 1;
    }
#pragma unroll
    for (int i = 0; i < FI; i++)
#pragma unroll
        for (int j = 0; j < 2; j++) {
            const int row = row0 + wr * (BM / 2) + i * 16 + lg * 4;
            const int col = col0 + wc * 32 + j * 16 + lr;
            const float b = bias[col];
            if (trans) {   // fused transpose: C^T[col][row..row+3] (fp16 only)
                half4 h;
#pragma unroll
                for (int rj = 0; rj < 4; rj++) h[rj] = (_Float16)((acc[i][j][rj] + b) * scale);
                *(half4*)((_Float16*)C + (size_t)col * S_LEN + row) = h;
            } else {
#pragma unroll
                for (int rj = 0; rj < 4; rj++) {
                    float v = (acc[i][j][rj] + b) * scale;
                    if constexpr (sizeof(OT) == 2)
                        C[(size_t)(row + rj) * DMODEL + col] = (OT)(_Float16)v;
                    else
                        C[(size_t)(row + rj) * DMODEL + col] = v;
                }
            }
        }
}

struct QKVArgs {
    const _Float16* A[3];
    const _Float16* W[3];
    const float*    bias[3];
    _Float16*       C[3];
    float           scale[3];
};

// grid 768: XCD remap -> sid; sid -> (z, by, bx), bx fastest (A-panel L2 reuse).
// z==2 (v projection) writes transposed -> Vt directly (no transpose kernel).
__global__ __launch_bounds__(256) void gemm_qkv(QKVArgs a) {
    const int nper = (int)gridDim.x >> 3;
    const int sid  = ((int)blockIdx.x & 7) * nper + ((int)blockIdx.x >> 3);
    const int z  = sid >> 8;
    const int r  = sid & 255;
    const int by = r >> 4, bx = r & 15;
    gemm_body<128, _Float16>(a.A[z], a.W[z], a.bias[z], a.C[z], a.scale[z], bx, by, z == 2);
}

__global__ __launch_bounds__(256) void gemm_out_k(const _Float16* __restrict__ A,
                                                  const _Float16* __restrict__ W,
                                                  const float* __restrict__ bias,
                                                  float* __restrict__ C) {
    const int nper = (int)gridDim.x >> 3;
    const int sid  = ((int)blockIdx.x & 7) * nper + ((int)blockIdx.x >> 3);
    const int by = sid >> 4, bx = sid & 15;
    gemm_body<64, float>(A, W, bias, C, 1.0f, bx, by, false);
}

// ---------------- causal flash attention ----------------
// R9-exact: grid (NCHUNK, NHEADS) 2-D, heavy chunks first. 512 thr = 8 waves
// x 32 q-rows. Each K/V ds_read feeds TWO MFMAs. LDS-staged K/V
// double-buffered. Swapped mfma(K,Q), exp2 domain, defer-max THR=8.
__global__ __launch_bounds__(512, 4) void attn_kernel(
    const _Float16* __restrict__ q,
    const _Float16* __restrict__ k,
    const _Float16* __restrict__ Vt,
    _Float16* __restrict__ Opart,   // [16][NCHUNK][256][64], normalized
    float2* __restrict__ ml,        // [16][NCHUNK][256]
    AttnMap map)
{
    __shared__ _Float16 Kl[2][64 * 64];
    __shared__ _Float16 Vl[2][64 * 64];
    __shared__ _Float16 P[8][32][72];
    const int tid = threadIdx.x, lane = tid & 63, wid = tid >> 6;
    const int x = NCHUNK - 1 - (int)blockIdx.x;   // heavy chunks first
    const int h = blockIdx.y;
    int qt = 0;
    while (map.base[qt + 1] <= x) qt++;
    const int c  = x - map.base[qt];
    const int q0 = qt * 256 + wid * 32;
    const int lr = lane & 15, lg = lane >> 4;
    const int srcb = lg * 20;

    const int r8 = lane >> 3, sl = lane & 7;
    const int ssw = (sl ^ r8) * 8;

    half8 qf[2][2];
#pragma unroll
    for (int qs = 0; qs < 2; qs++)
#pragma unroll
        for (int ds = 0; ds < 2; ds++)
            qf[qs][ds] = *(const half8*)(q + (size_t)(q0 + qs * 16 + lr) * DMODEL + h * HDIM + ds * 32 + lg * 8);

    float m[2] = {-1e30f, -1e30f}, lsum[2] = {0.0f, 0.0f};
    f32x4 od[2][4];
#pragma unroll
    for (int qs = 0; qs < 2; qs++)
#pragma unroll
        for (int dt = 0; dt < 4; dt++) od[qs][dt] = (f32x4)(0.0f);

    const int T4 = 4 * (qt + 1);
    const int t0 = c * CHUNK;
    const int t1 = (T4 < t0 + CHUNK) ? T4 : (t0 + CHUNK);

    auto stage = [&](int b, int t) {
        const int kb = t * 64;
        gload16(k + (size_t)(kb + wid * 8 + r8) * DMODEL + h * HDIM + ssw,
                &Kl[b][wid * 8 * 64]);
        gload16(Vt + (size_t)(h * HDIM + wid * 8 + r8) * S_LEN + kb + ssw,
                &Vl[b][wid * 8 * 64]);
    };

    int cur = 0;
    stage(0, t0);
    __syncthreads();

    for (int t = t0; t < t1; t++) {
        if (t + 1 < t1) stage(cur ^ 1, t + 1);
        const int k0 = t * 64;
        f32x4 sc[2][4];
#pragma unroll
        for (int qs = 0; qs < 2; qs++)
#pragma unroll
            for (int kt = 0; kt < 4; kt++) sc[qs][kt] = (f32x4)(0.0f);
        __builtin_amdgcn_s_setprio(1);
#pragma unroll
        for (int kt = 0; kt < 4; kt++)
#pragma unroll
            for (int ds = 0; ds < 2; ds++) {
                half8 kf = *(const half8*)(&Kl[cur][(kt * 16 + lr) * 64 + (((ds * 4 + lg) ^ (lr & 7)) * 8)]);
                sc[0][kt] = __builtin_amdgcn_mfma_f32_16x16x32_f16(kf, qf[0][ds], sc[0][kt], 0, 0, 0);
                sc[1][kt] = __builtin_amdgcn_mfma_f32_16x16x32_f16(kf, qf[1][ds], sc[1][kt], 0, 0, 0);
            }
        __builtin_amdgcn_s_setprio(0);
        // sc[qs][kt][r] = S[key=k0+kt*16+lg*4+r][q=q0+qs*16+lr]
        if (k0 + 63 > q0) {
#pragma unroll
            for (int qs = 0; qs < 2; qs++) {
                const int qrow = q0 + qs * 16 + lr;
#pragma unroll
                for (int kt = 0; kt < 4; kt++) {
                    const int kb2 = k0 + kt * 16 + lg * 4;
#pragma unroll
                    for (int r = 0; r < 4; r++)
                        if (kb2 + r > qrow) sc[qs][kt][r] = -1e30f;
                }
            }
        }
        float vmax[2];
#pragma unroll
        for (int qs = 0; qs < 2; qs++) {
            float mk[4];
#pragma unroll
            for (int kt = 0; kt < 4; kt++)
                mk[kt] = fmaxf(fmaxf(sc[qs][kt][0], sc[qs][kt][1]), fmaxf(sc[qs][kt][2], sc[qs][kt][3]));
            float v = fmaxf(fmaxf(mk[0], mk[1]), fmaxf(mk[2], mk[3]));
            v = fmaxf(v, __shfl_xor(v, 16));
            v = fmaxf(v, __shfl_xor(v, 32));
            vmax[qs] = v;
        }
        if (!__all(vmax[0] <= m[0] + 8.0f && vmax[1] <= m[1] + 8.0f)) {   // T13
#pragma unroll
            for (int qs = 0; qs < 2; qs++) {
                const float mnew = fmaxf(m[qs], vmax[qs]);
                const float sfac = exp2f(m[qs] - mnew);
                m[qs] = mnew;
                lsum[qs] *= sfac;
                float sf[4];
#pragma unroll
                for (int r = 0; r < 4; r++) sf[r] = __shfl(sfac, srcb + r);
#pragma unroll
                for (int dt = 0; dt < 4; dt++)
#pragma unroll
                    for (int r = 0; r < 4; r++) od[qs][dt][r] *= sf[r];
            }
        }
#pragma unroll
        for (int qs = 0; qs < 2; qs++) {
            float ps[4];
#pragma unroll
            for (int kt = 0; kt < 4; kt++) {
                float p0 = exp2f(sc[qs][kt][0] - m[qs]), p1 = exp2f(sc[qs][kt][1] - m[qs]);
                float p2 = exp2f(sc[qs][kt][2] - m[qs]), p3 = exp2f(sc[qs][kt][3] - m[qs]);
                sc[qs][kt][0] = p0; sc[qs][kt][1] = p1; sc[qs][kt][2] = p2; sc[qs][kt][3] = p3;
                ps[kt] = (p0 + p1) + (p2 + p3);
            }
            float psum = (ps[0] + ps[1]) + (ps[2] + ps[3]);
            psum += __shfl_xor(psum, 16);
            psum += __shfl_xor(psum, 32);
            lsum[qs] += psum;
#pragma unroll
            for (int kt = 0; kt < 4; kt++) {
                half4 ph;
#pragma unroll
                for (int r = 0; r < 4; r++) ph[r] = (_Float16)sc[qs][kt][r];
                *(half4*)(&P[wid][qs * 16 + lr][kt * 16 + lg * 4]) = ph;
            }
        }
        __builtin_amdgcn_s_setprio(1);
#pragma unroll
        for (int ks = 0; ks < 2; ks++) {
            half8 pa0 = *(const half8*)(&P[wid][lr][ks * 32 + lg * 8]);
            half8 pa1 = *(const half8*)(&P[wid][16 + lr][ks * 32 + lg * 8]);
#pragma unroll
            for (int dt = 0; dt < 4; dt++) {
                half8 vb = *(const half8*)(&Vl[cur][(dt * 16 + lr) * 64 + (((ks * 4 + lg) ^ (lr & 7)) * 8)]);
                od[0][dt] = __builtin_amdgcn_mfma_f32_16x16x32_f16(pa0, vb, od[0][dt], 0, 0, 0);
                od[1][dt] = __builtin_amdgcn_mfma_f32_16x16x32_f16(pa1, vb, od[1][dt], 0, 0, 0);
            }
        }
        __builtin_amdgcn_s_setprio(0);
        __syncthreads();
        cur ^= 1;
    }

    _Float16* Ob = Opart + ((size_t)h * NCHUNK + x) * 256 * 64;
#pragma unroll
    for (int qs = 0; qs < 2; qs++) {
        const float inv = 1.0f / lsum[qs];
        float invb[4];
#pragma unroll
        for (int r = 0; r < 4; r++) invb[r] = __shfl(inv, srcb + r);
#pragma unroll
        for (int dt = 0; dt < 4; dt++)
#pragma unroll
            for (int r = 0; r < 4; r++)
                Ob[(size_t)(wid * 32 + qs * 16 + lg * 4 + r) * 64 + dt * 16 + lr] =
                    (_Float16)(od[qs][dt][r] * invb[r]);
    }
    if (lane < 16) {
#pragma unroll
        for (int qs = 0; qs < 2; qs++) {
            float2 v; v.x = m[qs]; v.y = lsum[qs];
            ml[((size_t)h * NCHUNK + x) * 256 + wid * 32 + qs * 16 + lr] = v;
        }
    }
}

// ---------------- chunk combine: at[q][h*64+d] fp16 ----------------
__global__ __launch_bounds__(256) void combine_kernel(
    const _Float16* __restrict__ Opart, const float2* __restrict__ ml,
    _Float16* __restrict__ at, AttnMap map)
{
    const int idx = blockIdx.x * 256 + threadIdx.x;
    const int qrow = idx >> 7;
    const int c8 = (idx & 127) * 8;
    const int h = c8 >> 6, d = c8 & 63;
    const int qt = qrow >> 8;
    const int cb = map.base[qt];
    const int nc = map.base[qt + 1] - cb;
    const int lrow = qrow & 255;

    float M = -1e30f, denom = 0.0f;
    float acc[8];
#pragma unroll
    for (int j = 0; j < 8; j++) acc[j] = 0.0f;
    for (int cc = 0; cc < nc; cc++) {
        const size_t ci = (size_t)h * NCHUNK + cb + cc;
        const float2 mlv = ml[ci * 256 + lrow];
        half8 ov = *(const half8*)(Opart + (ci * 256 + lrow) * 64 + d);
        if (mlv.x > M) {
            const float r = exp2f(M - mlv.x);
            denom = denom * r + mlv.y;
#pragma unroll
            for (int j = 0; j < 8; j++) acc[j] = acc[j] * r + (float)ov[j] * mlv.y;
            M = mlv.x;
        } else {
            const float w = exp2f(mlv.x - M) * mlv.y;
            denom += w;
#pragma unroll
            for (int j = 0; j < 8; j++) acc[j] += (float)ov[j] * w;
        }
    }
    const float inv = 1.0f / denom;
    half8 o;
#pragma unroll
    for (int j = 0; j < 8; j++) o[j] = (_Float16)(acc[j] * inv);
    *(half8*)(at + (size_t)qrow * DMODEL + c8) = o;
}

// ---------------- launch ----------------
extern "C" void kernel_launch(void* const* d_in, const int* in_sizes, int n_in,
                              void* d_out, int out_size, void* d_ws, size_t ws_size,
                              hipStream_t stream) {
    const float* Q  = (const float*)d_in[0];
    const float* K  = (const float*)d_in[1];
    const float* V  = (const float*)d_in[2];
    const float* Wq = (const float*)d_in[3];
    const float* bq = (const float*)d_in[4];
    const float* Wk = (const float*)d_in[5];
    const float* bk = (const float*)d_in[6];
    const float* Wv = (const float*)d_in[7];
    const float* bv = (const float*)d_in[8];
    const float* Wo = (const float*)d_in[9];
    const float* bo = (const float*)d_in[10];

    // 32 MB workspace, liveness-aliased (MB offsets):
    //  0-4  : Vt  (qkv z2 transposed out -> attn)
    //  4-8  : qh  (qkv -> attn)          -> at (combine -> gemm_out)
    //  8-12 : kh  (qkv -> attn)
    // 12-14 : Woh (cvt -> gemm_out)
    // 14-30 : Qh/Kh/Vh/Wqh/Wkh (cvt -> qkv) -> Opart(16MB) (attn -> combine)
    // 30-32 : Wvh (cvt -> qkv)              -> ml(1MB)     (attn -> combine)
    char* w = (char*)d_ws;
    const size_t MB = 1 << 20;
    _Float16* Vt  = (_Float16*)(w + 0 * MB);
    _Float16* qh  = (_Float16*)(w + 4 * MB);
    _Float16* kh  = (_Float16*)(w + 8 * MB);
    _Float16* Woh = (_Float16*)(w + 12 * MB);
    _Float16* Qh  = (_Float16*)(w + 14 * MB);
    _Float16* Kh  = (_Float16*)(w + 18 * MB);
    _Float16* Vh  = (_Float16*)(w + 22 * MB);
    _Float16* Wqh = (_Float16*)(w + 26 * MB);
    _Float16* Wkh = (_Float16*)(w + 28 * MB);
    _Float16* Wvh = (_Float16*)(w + 30 * MB);
    _Float16* Opart = (_Float16*)(w + 14 * MB);   // 16 MB exactly
    float2*   ml    = (float2*)(w + 30 * MB);     // 1 MB
    _Float16* at    = qh;

    const size_t SD = (size_t)S_LEN * DMODEL;
    const size_t WD = (size_t)DMODEL * DMODEL;

    CvtArgs ca;
    ca.src[0] = Q;  ca.dst[0] = Qh;  ca.n[0] = (int)SD;
    ca.src[1] = K;  ca.dst[1] = Kh;  ca.n[1] = (int)SD;
    ca.src[2] = V;  ca.dst[2] = Vh;  ca.n[2] = (int)SD;
    ca.src[3] = Wq; ca.dst[3] = Wqh; ca.n[3] = (int)WD;
    ca.src[4] = Wk; ca.dst[4] = Wkh; ca.n[4] = (int)WD;
    ca.src[5] = Wv; ca.dst[5] = Wvh; ca.n[5] = (int)WD;
    ca.src[6] = Wo; ca.dst[6] = Woh; ca.n[6] = (int)WD;
    cvt_kernel<<<dim3(512, 1, 7), 256, 0, stream>>>(ca);

    QKVArgs ga;
    ga.A[0] = Qh; ga.W[0] = Wqh; ga.bias[0] = bq; ga.C[0] = qh; ga.scale[0] = 0.125f * LOG2E;
    ga.A[1] = Kh; ga.W[1] = Wkh; ga.bias[1] = bk; ga.C[1] = kh; ga.scale[1] = 1.0f;
    ga.A[2] = Vh; ga.W[2] = Wvh; ga.bias[2] = bv; ga.C[2] = Vt; ga.scale[2] = 1.0f;
    gemm_qkv<<<dim3(768), 256, 0, stream>>>(ga);

    AttnMap map;
    map.base[0] = 0;
    for (int qt = 0; qt < 8; qt++)
        map.base[qt + 1] = map.base[qt] + (4 * (qt + 1) + CHUNK - 1) / CHUNK;
    // map.base[8] == NCHUNK (32)

    attn_kernel<<<dim3(NCHUNK, NHEADS), 512, 0, stream>>>(qh, kh, Vt, Opart, ml, map);
    combine_kernel<<<dim3(1024), 256, 0, stream>>>(Opart, ml, at, map);
    gemm_out_k<<<dim3(512), 256, 0, stream>>>(at, Woh, bo, (float*)d_out);
}

// Round 16
// 79.442 us; speedup vs baseline: 1.0597x; 1.0020x over previous
//
#include <hip/hip_runtime.h>
#include <hip/hip_bf16.h>
#include <stdint.h>

#define S_LEN  2048
#define DMODEL 1024
#define NHEADS 16
#define HDIM   64
#define CHUNK  5      // k-tiles (64 keys) per attention chunk-block
#define NCHUNK 32     // sum over 8 q-tiles (256 rows) of ceil(4*(qt+1)/CHUNK); 512 blocks = exactly 2/CU
#define LOG2E  1.4426950408889634f

typedef __attribute__((ext_vector_type(8))) _Float16 half8;
typedef __attribute__((ext_vector_type(4))) _Float16 half4;
typedef __attribute__((ext_vector_type(4))) float    f32x4;

struct AttnMap { int base[9]; };

// ---------------- fp32 -> fp16 convert (7 tensors, one launch) ----------------
struct CvtArgs {
    const float* src[7];
    _Float16*    dst[7];
    int          n[7];
};

__global__ __launch_bounds__(256) void cvt_kernel(CvtArgs a) {
    const int z = blockIdx.z;
    const float* __restrict__ src = a.src[z];
    _Float16* __restrict__ dst = a.dst[z];
    const int n = a.n[z];
    const int stride = gridDim.x * blockDim.x * 8;
    for (int i = (blockIdx.x * blockDim.x + threadIdx.x) * 8; i < n; i += stride) {
        float4 v0 = *(const float4*)(src + i);
        float4 v1 = *(const float4*)(src + i + 4);
        half8 o;
        o[0] = (_Float16)v0.x; o[1] = (_Float16)v0.y;
        o[2] = (_Float16)v0.z; o[3] = (_Float16)v0.w;
        o[4] = (_Float16)v1.x; o[5] = (_Float16)v1.y;
        o[6] = (_Float16)v1.z; o[7] = (_Float16)v1.w;
        *(half8*)(dst + i) = o;
    }
}

// ---------------- GEMM: C[2048][1024] = A x W^T + bias ----------------
// Best-measured config (79.6us, reproduced): BM x 64 tile, BK=64, 4 waves
// (2x2). Double-buffered LDS, 2-phase pipeline (stage(t+1) BEFORE compute(t),
// one __syncthreads per k-tile). Both-sides XOR swizzle on 128B LDS rows.
// XCD-contiguous 1-D grid remap. setprio around MFMA cluster (R14 A/B:
// removal cost ~4.5us). TRANS mode writes C^T (fused V transpose).
__device__ __forceinline__ void gload16(const _Float16* g, _Float16* l) {
    __builtin_amdgcn_global_load_lds(
        (__attribute__((address_space(1))) void*)const_cast<_Float16*>(g),
        (__attribute__((address_space(3))) void*)l, 16, 0, 0);
}

template<int BM, typename OT>
__device__ __forceinline__ void gemm_body(
    const _Float16* __restrict__ A,
    const _Float16* __restrict__ W,
    const float*    __restrict__ bias,
    OT* __restrict__ C, float scale, int bx, int by, bool trans)
{
    constexpr int FI = BM / 32;
    __shared__ _Float16 As[2][BM * 64];
    __shared__ _Float16 Bs[2][64 * 64];
    const int tid  = threadIdx.x;
    const int lane = tid & 63, wid = tid >> 6;
    const int row0 = by * BM;
    const int col0 = bx * 64;
    const int wr = wid >> 1, wc = wid & 1;
    const int lr = lane & 15, lg = lane >> 4;
    const int sl = lane & 7;

    f32x4 acc[FI][2];
#pragma unroll
    for (int i = 0; i < FI; i++)
#pragma unroll
        for (int j = 0; j < 2; j++) acc[i][j] = (f32x4)(0.0f);

    auto stage = [&](int b, int k0) {
#pragma unroll
        for (int r = 0; r < BM / 32; r++) {
            const int base = r * 256 + wid * 64;
            const int row  = (base + lane) >> 3;
            gload16(A + (size_t)(row0 + row) * DMODEL + k0 + ((sl ^ (row & 7)) * 8),
                    &As[b][(size_t)base * 8]);
        }
#pragma unroll
        for (int r = 0; r < 2; r++) {
            const int base = r * 256 + wid * 64;
            const int row  = (base + lane) >> 3;
            gload16(W + (size_t)(col0 + row) * DMODEL + k0 + ((sl ^ (row & 7)) * 8),
                    &Bs[b][(size_t)base * 8]);
        }
    };

    stage(0, 0);
    __syncthreads();
    int cur = 0;
    for (int t = 0; t < DMODEL / 64; t++) {
        if (t + 1 < DMODEL / 64) stage(cur ^ 1, (t + 1) * 64);
#pragma unroll
        for (int ks = 0; ks < 2; ks++) {
            half8 af[FI], bf[2];
#pragma unroll
            for (int i = 0; i < FI; i++)
                af[i] = *(const half8*)(&As[cur][(wr * (BM / 2) + i * 16 + lr) * 64 + (((ks * 4 + lg) ^ (lr & 7)) * 8)]);
#pragma unroll
            for (int j = 0; j < 2; j++)
                bf[j] = *(const half8*)(&Bs[cur][(wc * 32 + j * 16 + lr) * 64 + (((ks * 4 + lg) ^ (lr & 7)) * 8)]);
            __builtin_amdgcn_s_setprio(1);
#pragma unroll
            for (int i = 0; i < FI; i++)
#pragma unroll
                for (int j = 0; j < 2; j++)
                    acc[i][j] = __builtin_amdgcn_mfma_f32_16x16x32_f16(af[i], bf[j], acc[i][j], 0, 0, 0);
            __builtin_amdgcn_s_setprio(0);
        }
        __syncthreads();
        cur ^= 1;
    }
#pragma unroll
    for (int i = 0; i < FI; i++)
#pragma unroll
        for (int j = 0; j < 2; j++) {
            const int row = row0 + wr * (BM / 2) + i * 16 + lg * 4;
            const int col = col0 + wc * 32 + j * 16 + lr;
            const float b = bias[col];
            if (trans) {   // fused transpose: C^T[col][row..row+3] (fp16 only)
                half4 h;
#pragma unroll
                for (int rj = 0; rj < 4; rj++) h[rj] = (_Float16)((acc[i][j][rj] + b) * scale);
                *(half4*)((_Float16*)C + (size_t)col * S_LEN + row) = h;
            } else {
#pragma unroll
                for (int rj = 0; rj < 4; rj++) {
                    float v = (acc[i][j][rj] + b) * scale;
                    if constexpr (sizeof(OT) == 2)
                        C[(size_t)(row + rj) * DMODEL + col] = (OT)(_Float16)v;
                    else
                        C[(size_t)(row + rj) * DMODEL + col] = v;
                }
            }
        }
}

struct QKVArgs {
    const _Float16* A[3];
    const _Float16* W[3];
    const float*    bias[3];
    _Float16*       C[3];
    float           scale[3];
};

// grid 768: XCD remap -> sid; sid -> (z, by, bx), bx fastest (A-panel L2 reuse).
// z==2 (v projection) writes transposed -> Vt directly (no transpose kernel).
__global__ __launch_bounds__(256) void gemm_qkv(QKVArgs a) {
    const int nper = (int)gridDim.x >> 3;
    const int sid  = ((int)blockIdx.x & 7) * nper + ((int)blockIdx.x >> 3);
    const int z  = sid >> 8;
    const int r  = sid & 255;
    const int by = r >> 4, bx = r & 15;
    gemm_body<128, _Float16>(a.A[z], a.W[z], a.bias[z], a.C[z], a.scale[z], bx, by, z == 2);
}

__global__ __launch_bounds__(256) void gemm_out_k(const _Float16* __restrict__ A,
                                                  const _Float16* __restrict__ W,
                                                  const float* __restrict__ bias,
                                                  float* __restrict__ C) {
    const int nper = (int)gridDim.x >> 3;
    const int sid  = ((int)blockIdx.x & 7) * nper + ((int)blockIdx.x >> 3);
    const int by = sid >> 4, bx = sid & 15;
    gemm_body<64, float>(A, W, bias, C, 1.0f, bx, by, false);
}

// ---------------- causal flash attention ----------------
// Best-measured config: grid (NCHUNK, NHEADS) 2-D, heavy chunks first.
// 512 thr = 8 waves x 32 q-rows. Each K/V ds_read feeds TWO MFMAs.
// LDS-staged K/V double-buffered (long compute phase covers barrier drain).
// Swapped mfma(K,Q), exp2 domain, defer-max THR=8 (T13). setprio (m191).
__global__ __launch_bounds__(512, 4) void attn_kernel(
    const _Float16* __restrict__ q,
    const _Float16* __restrict__ k,
    const _Float16* __restrict__ Vt,
    _Float16* __restrict__ Opart,   // [16][NCHUNK][256][64], normalized
    float2* __restrict__ ml,        // [16][NCHUNK][256]
    AttnMap map)
{
    __shared__ _Float16 Kl[2][64 * 64];
    __shared__ _Float16 Vl[2][64 * 64];
    __shared__ _Float16 P[8][32][72];
    const int tid = threadIdx.x, lane = tid & 63, wid = tid >> 6;
    const int x = NCHUNK - 1 - (int)blockIdx.x;   // heavy chunks first
    const int h = blockIdx.y;
    int qt = 0;
    while (map.base[qt + 1] <= x) qt++;
    const int c  = x - map.base[qt];
    const int q0 = qt * 256 + wid * 32;
    const int lr = lane & 15, lg = lane >> 4;
    const int srcb = lg * 20;

    const int r8 = lane >> 3, sl = lane & 7;
    const int ssw = (sl ^ r8) * 8;

    half8 qf[2][2];
#pragma unroll
    for (int qs = 0; qs < 2; qs++)
#pragma unroll
        for (int ds = 0; ds < 2; ds++)
            qf[qs][ds] = *(const half8*)(q + (size_t)(q0 + qs * 16 + lr) * DMODEL + h * HDIM + ds * 32 + lg * 8);

    float m[2] = {-1e30f, -1e30f}, lsum[2] = {0.0f, 0.0f};
    f32x4 od[2][4];
#pragma unroll
    for (int qs = 0; qs < 2; qs++)
#pragma unroll
        for (int dt = 0; dt < 4; dt++) od[qs][dt] = (f32x4)(0.0f);

    const int T4 = 4 * (qt + 1);
    const int t0 = c * CHUNK;
    const int t1 = (T4 < t0 + CHUNK) ? T4 : (t0 + CHUNK);

    auto stage = [&](int b, int t) {
        const int kb = t * 64;
        gload16(k + (size_t)(kb + wid * 8 + r8) * DMODEL + h * HDIM + ssw,
                &Kl[b][wid * 8 * 64]);
        gload16(Vt + (size_t)(h * HDIM + wid * 8 + r8) * S_LEN + kb + ssw,
                &Vl[b][wid * 8 * 64]);
    };

    int cur = 0;
    stage(0, t0);
    __syncthreads();

    for (int t = t0; t < t1; t++) {
        if (t + 1 < t1) stage(cur ^ 1, t + 1);
        const int k0 = t * 64;
        f32x4 sc[2][4];
#pragma unroll
        for (int qs = 0; qs < 2; qs++)
#pragma unroll
            for (int kt = 0; kt < 4; kt++) sc[qs][kt] = (f32x4)(0.0f);
        __builtin_amdgcn_s_setprio(1);
#pragma unroll
        for (int kt = 0; kt < 4; kt++)
#pragma unroll
            for (int ds = 0; ds < 2; ds++) {
                half8 kf = *(const half8*)(&Kl[cur][(kt * 16 + lr) * 64 + (((ds * 4 + lg) ^ (lr & 7)) * 8)]);
                sc[0][kt] = __builtin_amdgcn_mfma_f32_16x16x32_f16(kf, qf[0][ds], sc[0][kt], 0, 0, 0);
                sc[1][kt] = __builtin_amdgcn_mfma_f32_16x16x32_f16(kf, qf[1][ds], sc[1][kt], 0, 0, 0);
            }
        __builtin_amdgcn_s_setprio(0);
        // sc[qs][kt][r] = S[key=k0+kt*16+lg*4+r][q=q0+qs*16+lr]
        if (k0 + 63 > q0) {
#pragma unroll
            for (int qs = 0; qs < 2; qs++) {
                const int qrow = q0 + qs * 16 + lr;
#pragma unroll
                for (int kt = 0; kt < 4; kt++) {
                    const int kb2 = k0 + kt * 16 + lg * 4;
#pragma unroll
                    for (int r = 0; r < 4; r++)
                        if (kb2 + r > qrow) sc[qs][kt][r] = -1e30f;
                }
            }
        }
        float vmax[2];
#pragma unroll
        for (int qs = 0; qs < 2; qs++) {
            float mk[4];
#pragma unroll
            for (int kt = 0; kt < 4; kt++)
                mk[kt] = fmaxf(fmaxf(sc[qs][kt][0], sc[qs][kt][1]), fmaxf(sc[qs][kt][2], sc[qs][kt][3]));
            float v = fmaxf(fmaxf(mk[0], mk[1]), fmaxf(mk[2], mk[3]));
            v = fmaxf(v, __shfl_xor(v, 16));
            v = fmaxf(v, __shfl_xor(v, 32));
            vmax[qs] = v;
        }
        if (!__all(vmax[0] <= m[0] + 8.0f && vmax[1] <= m[1] + 8.0f)) {   // T13
#pragma unroll
            for (int qs = 0; qs < 2; qs++) {
                const float mnew = fmaxf(m[qs], vmax[qs]);
                const float sfac = exp2f(m[qs] - mnew);
                m[qs] = mnew;
                lsum[qs] *= sfac;
                float sf[4];
#pragma unroll
                for (int r = 0; r < 4; r++) sf[r] = __shfl(sfac, srcb + r);
#pragma unroll
                for (int dt = 0; dt < 4; dt++)
#pragma unroll
                    for (int r = 0; r < 4; r++) od[qs][dt][r] *= sf[r];
            }
        }
#pragma unroll
        for (int qs = 0; qs < 2; qs++) {
            float ps[4];
#pragma unroll
            for (int kt = 0; kt < 4; kt++) {
                float p0 = exp2f(sc[qs][kt][0] - m[qs]), p1 = exp2f(sc[qs][kt][1] - m[qs]);
                float p2 = exp2f(sc[qs][kt][2] - m[qs]), p3 = exp2f(sc[qs][kt][3] - m[qs]);
                sc[qs][kt][0] = p0; sc[qs][kt][1] = p1; sc[qs][kt][2] = p2; sc[qs][kt][3] = p3;
                ps[kt] = (p0 + p1) + (p2 + p3);
            }
            float psum = (ps[0] + ps[1]) + (ps[2] + ps[3]);
            psum += __shfl_xor(psum, 16);
            psum += __shfl_xor(psum, 32);
            lsum[qs] += psum;
#pragma unroll
            for (int kt = 0; kt < 4; kt++) {
                half4 ph;
#pragma unroll
                for (int r = 0; r < 4; r++) ph[r] = (_Float16)sc[qs][kt][r];
                *(half4*)(&P[wid][qs * 16 + lr][kt * 16 + lg * 4]) = ph;
            }
        }
        __builtin_amdgcn_s_setprio(1);
#pragma unroll
        for (int ks = 0; ks < 2; ks++) {
            half8 pa0 = *(const half8*)(&P[wid][lr][ks * 32 + lg * 8]);
            half8 pa1 = *(const half8*)(&P[wid][16 + lr][ks * 32 + lg * 8]);
#pragma unroll
            for (int dt = 0; dt < 4; dt++) {
                half8 vb = *(const half8*)(&Vl[cur][(dt * 16 + lr) * 64 + (((ks * 4 + lg) ^ (lr & 7)) * 8)]);
                od[0][dt] = __builtin_amdgcn_mfma_f32_16x16x32_f16(pa0, vb, od[0][dt], 0, 0, 0);
                od[1][dt] = __builtin_amdgcn_mfma_f32_16x16x32_f16(pa1, vb, od[1][dt], 0, 0, 0);
            }
        }
        __builtin_amdgcn_s_setprio(0);
        __syncthreads();
        cur ^= 1;
    }

    _Float16* Ob = Opart + ((size_t)h * NCHUNK + x) * 256 * 64;
#pragma unroll
    for (int qs = 0; qs < 2; qs++) {
        const float inv = 1.0f / lsum[qs];
        float invb[4];
#pragma unroll
        for (int r = 0; r < 4; r++) invb[r] = __shfl(inv, srcb + r);
#pragma unroll
        for (int dt = 0; dt < 4; dt++)
#pragma unroll
            for (int r = 0; r < 4; r++)
                Ob[(size_t)(wid * 32 + qs * 16 + lg * 4 + r) * 64 + dt * 16 + lr] =
                    (_Float16)(od[qs][dt][r] * invb[r]);
    }
    if (lane < 16) {
#pragma unroll
        for (int qs = 0; qs < 2; qs++) {
            float2 v; v.x = m[qs]; v.y = lsum[qs];
            ml[((size_t)h * NCHUNK + x) * 256 + wid * 32 + qs * 16 + lr] = v;
        }
    }
}

// ---------------- chunk combine: at[q][h*64+d] fp16 ----------------
__global__ __launch_bounds__(256) void combine_kernel(
    const _Float16* __restrict__ Opart, const float2* __restrict__ ml,
    _Float16* __restrict__ at, AttnMap map)
{
    const int idx = blockIdx.x * 256 + threadIdx.x;
    const int qrow = idx >> 7;
    const int c8 = (idx & 127) * 8;
    const int h = c8 >> 6, d = c8 & 63;
    const int qt = qrow >> 8;
    const int cb = map.base[qt];
    const int nc = map.base[qt + 1] - cb;
    const int lrow = qrow & 255;

    float M = -1e30f, denom = 0.0f;
    float acc[8];
#pragma unroll
    for (int j = 0; j < 8; j++) acc[j] = 0.0f;
    for (int cc = 0; cc < nc; cc++) {
        const size_t ci = (size_t)h * NCHUNK + cb + cc;
        const float2 mlv = ml[ci * 256 + lrow];
        half8 ov = *(const half8*)(Opart + (ci * 256 + lrow) * 64 + d);
        if (mlv.x > M) {
            const float r = exp2f(M - mlv.x);
            denom = denom * r + mlv.y;
#pragma unroll
            for (int j = 0; j < 8; j++) acc[j] = acc[j] * r + (float)ov[j] * mlv.y;
            M = mlv.x;
        } else {
            const float w = exp2f(mlv.x - M) * mlv.y;
            denom += w;
#pragma unroll
            for (int j = 0; j < 8; j++) acc[j] += (float)ov[j] * w;
        }
    }
    const float inv = 1.0f / denom;
    half8 o;
#pragma unroll
    for (int j = 0; j < 8; j++) o[j] = (_Float16)(acc[j] * inv);
    *(half8*)(at + (size_t)qrow * DMODEL + c8) = o;
}

// ---------------- launch ----------------
extern "C" void kernel_launch(void* const* d_in, const int* in_sizes, int n_in,
                              void* d_out, int out_size, void* d_ws, size_t ws_size,
                              hipStream_t stream) {
    const float* Q  = (const float*)d_in[0];
    const float* K  = (const float*)d_in[1];
    const float* V  = (const float*)d_in[2];
    const float* Wq = (const float*)d_in[3];
    const float* bq = (const float*)d_in[4];
    const float* Wk = (const float*)d_in[5];
    const float* bk = (const float*)d_in[6];
    const float* Wv = (const float*)d_in[7];
    const float* bv = (const float*)d_in[8];
    const float* Wo = (const float*)d_in[9];
    const float* bo = (const float*)d_in[10];

    // 32 MB workspace, liveness-aliased (MB offsets):
    //  0-4  : Vt  (qkv z2 transposed out -> attn)
    //  4-8  : qh  (qkv -> attn)          -> at (combine -> gemm_out)
    //  8-12 : kh  (qkv -> attn)
    // 12-14 : Woh (cvt -> gemm_out)
    // 14-30 : Qh/Kh/Vh/Wqh/Wkh (cvt -> qkv) -> Opart(16MB) (attn -> combine)
    // 30-32 : Wvh (cvt -> qkv)              -> ml(1MB)     (attn -> combine)
    char* w = (char*)d_ws;
    const size_t MB = 1 << 20;
    _Float16* Vt  = (_Float16*)(w + 0 * MB);
    _Float16* qh  = (_Float16*)(w + 4 * MB);
    _Float16* kh  = (_Float16*)(w + 8 * MB);
    _Float16* Woh = (_Float16*)(w + 12 * MB);
    _Float16* Qh  = (_Float16*)(w + 14 * MB);
    _Float16* Kh  = (_Float16*)(w + 18 * MB);
    _Float16* Vh  = (_Float16*)(w + 22 * MB);
    _Float16* Wqh = (_Float16*)(w + 26 * MB);
    _Float16* Wkh = (_Float16*)(w + 28 * MB);
    _Float16* Wvh = (_Float16*)(w + 30 * MB);
    _Float16* Opart = (_Float16*)(w + 14 * MB);   // 16 MB exactly
    float2*   ml    = (float2*)(w + 30 * MB);     // 1 MB
    _Float16* at    = qh;

    const size_t SD = (size_t)S_LEN * DMODEL;
    const size_t WD = (size_t)DMODEL * DMODEL;

    CvtArgs ca;
    ca.src[0] = Q;  ca.dst[0] = Qh;  ca.n[0] = (int)SD;
    ca.src[1] = K;  ca.dst[1] = Kh;  ca.n[1] = (int)SD;
    ca.src[2] = V;  ca.dst[2] = Vh;  ca.n[2] = (int)SD;
    ca.src[3] = Wq; ca.dst[3] = Wqh; ca.n[3] = (int)WD;
    ca.src[4] = Wk; ca.dst[4] = Wkh; ca.n[4] = (int)WD;
    ca.src[5] = Wv; ca.dst[5] = Wvh; ca.n[5] = (int)WD;
    ca.src[6] = Wo; ca.dst[6] = Woh; ca.n[6] = (int)WD;
    cvt_kernel<<<dim3(512, 1, 7), 256, 0, stream>>>(ca);

    QKVArgs ga;
    ga.A[0] = Qh; ga.W[0] = Wqh; ga.bias[0] = bq; ga.C[0] = qh; ga.scale[0] = 0.125f * LOG2E;
    ga.A[1] = Kh; ga.W[1] = Wkh; ga.bias[1] = bk; ga.C[1] = kh; ga.scale[1] = 1.0f;
    ga.A[2] = Vh; ga.W[2] = Wvh; ga.bias[2] = bv; ga.C[2] = Vt; ga.scale[2] = 1.0f;
    gemm_qkv<<<dim3(768), 256, 0, stream>>>(ga);

    AttnMap map;
    map.base[0] = 0;
    for (int qt = 0; qt < 8; qt++)
        map.base[qt + 1] = map.base[qt] + (4 * (qt + 1) + CHUNK - 1) / CHUNK;
    // map.base[8] == NCHUNK (32)

    attn_kernel<<<dim3(NCHUNK, NHEADS), 512, 0, stream>>>(qh, kh, Vt, Opart, ml, map);
    combine_kernel<<<dim3(1024), 256, 0, stream>>>(Opart, ml, at, map);
    gemm_out_k<<<dim3(512), 256, 0, stream>>>(at, Woh, bo, (float*)d_out);
}